// Round 14
// baseline (559.646 us; speedup 1.0000x reference)
//
#include <hip/hip_runtime.h>

typedef unsigned int uint;
typedef unsigned short ushort;

#define AB_U 132  // A/B row stride in uints (264 bf16 elems, 257 used)

typedef __attribute__((ext_vector_type(8))) short short8;
typedef __attribute__((ext_vector_type(4))) float f32x4;
union U4S8 { uint4 u; short8 s; };

__device__ __forceinline__ ushort f2bf(float f) {
    uint u = __float_as_uint(f);
    u += 0x7FFFu + ((u >> 16) & 1u);   // round-to-nearest-even
    return (ushort)(u >> 16);
}
__device__ __forceinline__ float bf2f_lo(uint p) { return __uint_as_float(p << 16); }
__device__ __forceinline__ float bf2f_hi(uint p) { return __uint_as_float(p & 0xFFFF0000u); }
__device__ __forceinline__ uint packbf(float lo, float hi) {
    return (uint)f2bf(lo) | ((uint)f2bf(hi) << 16);
}

// ---------------- precompute: temb MLP + rank-2 edge-lin factors ----------------
__global__ __launch_bounds__(256) void precompute_kernel(
    const float* __restrict__ t,
    const float* __restrict__ We, const float* __restrict__ be,
    const float* __restrict__ Wo, const float* __restrict__ bo,
    const float* __restrict__ Wl1, const float* __restrict__ bl1,
    const float* __restrict__ Wl2, const float* __restrict__ bl2,
    const float* __restrict__ Wl3, const float* __restrict__ bl3,
    const float* __restrict__ Wt1, const float* __restrict__ bt1,
    const float* __restrict__ Wt2, const float* __restrict__ bt2,
    float* __restrict__ wsmall)
{
    __shared__ float t0[128];
    __shared__ float y1[256];
    int tid = threadIdx.x;
    float tt = t[0] * 4.0f;
    if (tid < 64) {
        float f = expf(-logf(10000.0f) * (float)tid / 63.0f);
        float v = tt * f;
        t0[tid]      = sinf(v);
        t0[tid + 64] = cosf(v);
    }
    __syncthreads();
    {
        float acc = bt1[tid];
        for (int k = 0; k < 128; k++) acc = fmaf(t0[k], Wt1[k * 256 + tid], acc);
        y1[tid] = fmaxf(acc, 0.0f);
    }
    __syncthreads();
    if (tid < 128) {
        float a = bt2[tid];
        for (int k = 0; k < 256; k++) a = fmaf(y1[k], Wt2[k * 128 + tid], a);
        wsmall[tid] = a;  // temb
    }
    {
        int j = tid & 127;
        const float* Wl  = (tid < 128) ? Wl2 : Wl3;
        const float* blp = (tid < 128) ? bl2 : bl3;
        float p = 0.f, q = 0.f, r = blp[j];
        for (int k = 0; k < 64; k++) {
            float w1 = Wl[k * 128 + j], w2 = Wl[(64 + k) * 128 + j];
            p = fmaf(We[k], w1, p);
            q = fmaf(Wo[k], w2, q);
            r = fmaf(be[k], w1, r);
            r = fmaf(bo[k], w2, r);
        }
        int base = (tid < 128) ? 128 : 512;
        wsmall[base + j]       = p;
        wsmall[base + 128 + j] = q;
        wsmall[base + 256 + j] = r;
    }
    if (tid == 0) {
        float p1 = 0.f, q1 = 0.f, r1 = bl1[0];
        for (int k = 0; k < 64; k++) {
            p1 = fmaf(We[k], Wl1[k], p1);
            q1 = fmaf(Wo[k], Wl1[64 + k], q1);
            r1 = fmaf(be[k], Wl1[k], r1);
            r1 = fmaf(bo[k], Wl1[64 + k], r1);
        }
        wsmall[896] = p1; wsmall[897] = q1; wsmall[898] = r1;
    }
}

// merged weight staging: c<512 -> Wd1 (A|B cols), 512..639 -> Wn2, 640..767 -> Wn3
__global__ __launch_bounds__(64) void stage_kernel(
    const float* __restrict__ Wd1, const float* __restrict__ Wn2,
    const float* __restrict__ Wn3, uint* __restrict__ Wt16u,
    uint* __restrict__ Wn2t16u, uint* __restrict__ Wn3t16u)
{
    int c = blockIdx.x, u = threadIdx.x, k = u * 2;
    if (c < 256) {
        Wt16u[c * 64 + u] = packbf(Wd1[k * 257 + c], Wd1[(k + 1) * 257 + c]);
    } else if (c < 512) {
        int cc = c - 256;
        Wt16u[c * 64 + u] = packbf(Wd1[(128 + k) * 257 + cc], Wd1[(128 + k + 1) * 257 + cc]);
    } else if (c < 640) {
        int cc = c - 512;
        Wn2t16u[cc * 64 + u] = packbf(Wn2[k * 128 + cc], Wn2[(k + 1) * 128 + cc]);
    } else {
        int cc = c - 640;
        Wn3t16u[cc * 64 + u] = packbf(Wn3[k * 128 + cc], Wn3[(k + 1) * 128 + cc]);
    }
}

// ---------------- CSR build: histogram -> hierarchical scan -> scatter ----------------
__global__ __launch_bounds__(256) void hist_kernel(
    const int* __restrict__ dst, int* __restrict__ cnt, int E)
{
    int e = blockIdx.x * blockDim.x + threadIdx.x;
    if (e < E) atomicAdd(&cnt[dst[e]], 1);
}

__global__ __launch_bounds__(256) void scan1_kernel(
    const int* __restrict__ cnt, int* __restrict__ rowstart,
    int* __restrict__ partials, int N)
{
    __shared__ int wsum[4];
    int b = blockIdx.x;
    int tid = threadIdx.x, lane = tid & 63, w = tid >> 6;
    int i0 = b * 1024 + tid * 4;
    int v0 = (i0     < N) ? cnt[i0]     : 0;
    int v1 = (i0 + 1 < N) ? cnt[i0 + 1] : 0;
    int v2 = (i0 + 2 < N) ? cnt[i0 + 2] : 0;
    int v3 = (i0 + 3 < N) ? cnt[i0 + 3] : 0;
    int tsum = v0 + v1 + v2 + v3;
    int s = tsum;
#pragma unroll
    for (int off = 1; off < 64; off <<= 1) {
        int u = __shfl_up(s, off, 64);
        if (lane >= off) s += u;
    }
    if (lane == 63) wsum[w] = s;
    __syncthreads();
    int woff = 0;
    for (int k = 0; k < w; k++) woff += wsum[k];
    int ex = woff + s - tsum;
    if (i0     < N) rowstart[i0]     = ex;
    if (i0 + 1 < N) rowstart[i0 + 1] = ex + v0;
    if (i0 + 2 < N) rowstart[i0 + 2] = ex + v0 + v1;
    if (i0 + 3 < N) rowstart[i0 + 3] = ex + v0 + v1 + v2;
    if (tid == 255) partials[b] = woff + s;
}

__global__ __launch_bounds__(64) void scan2_kernel(
    int* __restrict__ partials, int* __restrict__ rowstart, int nblk, int N)
{
    int lane = threadIdx.x;
    int carry = 0;
    for (int base = 0; base < nblk; base += 64) {
        int i = base + lane;
        int v = (i < nblk) ? partials[i] : 0;
        int s = v;
#pragma unroll
        for (int off = 1; off < 64; off <<= 1) {
            int u = __shfl_up(s, off, 64);
            if (lane >= off) s += u;
        }
        if (i < nblk) partials[i] = carry + s - v;
        carry += __shfl(s, 63, 64);
    }
    if (lane == 0) rowstart[N] = carry;
}

__global__ __launch_bounds__(256) void scan3_kernel(
    int* __restrict__ rowstart, const int* __restrict__ partials, int N)
{
    int i = blockIdx.x * blockDim.x + threadIdx.x;
    if (i < N) rowstart[i] += partials[i >> 10];
}

__global__ __launch_bounds__(256) void scatter_kernel(
    const int* __restrict__ src, const int* __restrict__ dst,
    const float* __restrict__ ea, const float* __restrict__ qy,
    const int* __restrict__ rowstart, int* __restrict__ cursor,
    uint4* __restrict__ epack, int E)
{
    int e = blockIdx.x * blockDim.x + threadIdx.x;
    if (e >= E) return;
    int d = dst[e];
    int pos = atomicAdd(&cursor[d], 1);
    uint4 pk;
    pk.x = (uint)e;
    pk.y = (uint)src[e];
    pk.z = __float_as_uint(ea[e]);
    pk.w = __float_as_uint(qy[e]);
    epack[rowstart[d] + pos] = pk;
}

// ---------------- layer 1 (scalar channel), pull over CSR, unroll 2 ----------------
__global__ __launch_bounds__(256) void edge1_kernel(
    const float* __restrict__ x, const uint4* __restrict__ epack,
    const int* __restrict__ rowstart, const float* __restrict__ scal,
    float* __restrict__ agg1, int N)
{
    int v = blockIdx.x * blockDim.x + threadIdx.x;
    if (v >= N) return;
    float s0 = scal[0], s1 = scal[1], s2 = scal[2];
    int beg = rowstart[v], end = rowstart[v + 1];
    float m = 0.0f;
    int i = beg;
    for (; i + 2 <= end; i += 2) {
        uint4 pk0 = epack[i];
        uint4 pk1 = epack[i + 1];
        float x0 = x[(int)pk0.y];
        float x1 = x[(int)pk1.y];
        m += fmaxf(x0 + fmaf(__uint_as_float(pk0.z), s0, fmaf(__uint_as_float(pk0.w), s1, s2)), 0.0f);
        m += fmaxf(x1 + fmaf(__uint_as_float(pk1.z), s0, fmaf(__uint_as_float(pk1.w), s1, s2)), 0.0f);
    }
    if (i < end) {
        uint4 pk = epack[i];
        m += fmaxf(x[(int)pk.y] + fmaf(__uint_as_float(pk.z), s0, fmaf(__uint_as_float(pk.w), s1, s2)), 0.0f);
    }
    agg1[v] = m;
}

// h1 = (x+agg1)*Wn1 + bn1 + temb -> bf16 shadow only
__global__ __launch_bounds__(256) void node1_kernel(
    const float* __restrict__ x, const float* __restrict__ agg1,
    const float* __restrict__ Wn1, const float* __restrict__ bn1,
    const float* __restrict__ temb, uint* __restrict__ h16u, int N)
{
    int i = blockIdx.x * blockDim.x + threadIdx.x;  // N*64 threads
    int n = i >> 6, j2 = (i & 63) * 2;
    if (n >= N) return;
    float v = x[n] + agg1[n];
    float h0 = fmaf(v, Wn1[j2],     bn1[j2]     + temb[j2]);
    float h1 = fmaf(v, Wn1[j2 + 1], bn1[j2 + 1] + temb[j2 + 1]);
    h16u[(size_t)n * 64 + (j2 >> 1)] = packbf(h0, h1);
}

// helper: per-wave edge aggregation for one node -> (accx, accy) at col pair `lane`
__device__ __forceinline__ void agg_node(
    const uint* __restrict__ hsrc, const uint4* __restrict__ epack,
    int beg, int end, int lane, float2 Pv, float2 Qv, float2 Rv,
    float& accx, float& accy)
{
    int i = beg;
    for (; i + 8 <= end; i += 8) {
        uint4 pk[8];
        uint hp[8];
#pragma unroll
        for (int j = 0; j < 8; j++) pk[j] = epack[i + j];
#pragma unroll
        for (int j = 0; j < 8; j++) hp[j] = hsrc[(size_t)pk[j].y * 64 + lane];
#pragma unroll
        for (int j = 0; j < 8; j++) {
            float a = __uint_as_float(pk[j].z), b = __uint_as_float(pk[j].w);
            accx += fmaxf(bf2f_lo(hp[j]) + fmaf(a, Pv.x, fmaf(b, Qv.x, Rv.x)), 0.0f);
            accy += fmaxf(bf2f_hi(hp[j]) + fmaf(a, Pv.y, fmaf(b, Qv.y, Rv.y)), 0.0f);
        }
    }
    for (; i + 2 <= end; i += 2) {
        uint4 pk0 = epack[i];
        uint4 pk1 = epack[i + 1];
        uint hp0 = hsrc[(size_t)pk0.y * 64 + lane];
        uint hp1 = hsrc[(size_t)pk1.y * 64 + lane];
        float a0 = __uint_as_float(pk0.z), b0 = __uint_as_float(pk0.w);
        float a1 = __uint_as_float(pk1.z), b1 = __uint_as_float(pk1.w);
        accx += fmaxf(bf2f_lo(hp0) + fmaf(a0, Pv.x, fmaf(b0, Qv.x, Rv.x)), 0.0f);
        accy += fmaxf(bf2f_hi(hp0) + fmaf(a0, Pv.y, fmaf(b0, Qv.y, Rv.y)), 0.0f);
        accx += fmaxf(bf2f_lo(hp1) + fmaf(a1, Pv.x, fmaf(b1, Qv.x, Rv.x)), 0.0f);
        accy += fmaxf(bf2f_hi(hp1) + fmaf(a1, Pv.y, fmaf(b1, Qv.y, Rv.y)), 0.0f);
    }
    if (i < end) {
        uint4 pk = epack[i];
        float a = __uint_as_float(pk.z), b = __uint_as_float(pk.w);
        uint hp = hsrc[(size_t)pk.y * 64 + lane];
        accx += fmaxf(bf2f_lo(hp) + fmaf(a, Pv.x, fmaf(b, Qv.x, Rv.x)), 0.0f);
        accy += fmaxf(bf2f_hi(hp) + fmaf(a, Pv.y, fmaf(b, Qv.y, Rv.y)), 0.0f);
    }
}

// ---- fused layer-2: per-wave aggregation (16 nodes/block) + MFMA node update ----
__global__ __launch_bounds__(1024) void aggnode2_kernel(
    const uint* __restrict__ hA, const uint4* __restrict__ epack,
    const int* __restrict__ rowstart,
    const float* __restrict__ P, const float* __restrict__ Q,
    const float* __restrict__ R, const uint* __restrict__ Wn2t16u,
    const float* __restrict__ bn, const float* __restrict__ temb,
    uint* __restrict__ hB, int N)
{
    __shared__ uint vs16[16][68];
    int nb = blockIdx.x * 16;
    int tid = threadIdx.x;
    int w = tid >> 6, lane = tid & 63;
    int v = nb + w;
    {
        int c = lane * 2;
        float2 Pv = *(const float2*)(P + c);
        float2 Qv = *(const float2*)(Q + c);
        float2 Rv = *(const float2*)(R + c);
        float accx = 0.0f, accy = 0.0f;
        uint hp = 0;
        if (v < N) {
            agg_node(hA, epack, rowstart[v], rowstart[v + 1], lane, Pv, Qv, Rv, accx, accy);
            hp = hA[(size_t)v * 64 + lane];
        }
        vs16[w][lane] = packbf(bf2f_lo(hp) + accx, bf2f_hi(hp) + accy);
    }
    __syncthreads();
    if (w < 8) {
        int cl = lane & 15, g = lane >> 4;
        short8 afr[4];
#pragma unroll
        for (int kc = 0; kc < 4; kc++) {
            U4S8 t;
            t.u = *(const uint4*)(&vs16[cl][kc * 16 + g * 4]);
            afr[kc] = t.s;
        }
        int c = w * 16 + cl;
        float bias = bn[c] + temb[c];
        f32x4 acc = {bias, bias, bias, bias};
#pragma unroll
        for (int kc = 0; kc < 4; kc++) {
            U4S8 t;
            t.u = *(const uint4*)(Wn2t16u + (size_t)c * 64 + kc * 16 + g * 4);
            acc = __builtin_amdgcn_mfma_f32_16x16x32_bf16(afr[kc], t.s, acc, 0, 0, 0);
        }
#pragma unroll
        for (int r = 0; r < 4; r++) {
            int n = nb + g * 4 + r;
            float val = acc[r];
            float nbr = __shfl_down(val, 1, 64);
            if (n < N && (cl & 1) == 0)
                hB[(size_t)n * 64 + (c >> 1)] = packbf(val, nbr);
        }
    }
}

// ---- fused layer-3: aggregation + node MFMA + decode A/B precompute + copy-out ----
__global__ __launch_bounds__(1024) void aggnode3_kernel(
    const uint* __restrict__ hB, const uint4* __restrict__ epack,
    const int* __restrict__ rowstart,
    const float* __restrict__ P, const float* __restrict__ Q,
    const float* __restrict__ R, const uint* __restrict__ Wn3t16u,
    const float* __restrict__ bn3, const float* __restrict__ temb,
    const uint* __restrict__ Wt16u, const float* __restrict__ Wd1,
    const float* __restrict__ bd1, uint* __restrict__ A16u,
    uint* __restrict__ B16u, int N)
{
    __shared__ uint vs16[16][68];
    __shared__ float hs3[16][132];
    __shared__ uint stA[16 * 132];
    __shared__ uint stB[16 * 132];
    int nb = blockIdx.x * 16;
    int tid = threadIdx.x;
    int w = tid >> 6, lane = tid & 63;
    int v = nb + w;
    {
        int c = lane * 2;
        float2 Pv = *(const float2*)(P + c);
        float2 Qv = *(const float2*)(Q + c);
        float2 Rv = *(const float2*)(R + c);
        float accx = 0.0f, accy = 0.0f;
        uint hp = 0;
        if (v < N) {
            agg_node(hB, epack, rowstart[v], rowstart[v + 1], lane, Pv, Qv, Rv, accx, accy);
            hp = hB[(size_t)v * 64 + lane];
        }
        vs16[w][lane] = packbf(bf2f_lo(hp) + accx, bf2f_hi(hp) + accy);
    }
    __syncthreads();
    // phase 1 (MFMA, first 4 waves): h3 = vs @ Wn3 + bn3 + temb -> hs3 f32
    if (tid < 256) {
        int wv = w, cl = lane & 15, g = lane >> 4;
        short8 afr[4];
#pragma unroll
        for (int kc = 0; kc < 4; kc++) {
            U4S8 t;
            t.u = *(const uint4*)(&vs16[cl][kc * 16 + g * 4]);
            afr[kc] = t.s;
        }
#pragma unroll
        for (int tt = 0; tt < 2; tt++) {
            int c = wv * 32 + tt * 16 + cl;
            float bias = bn3[c] + temb[c];
            f32x4 acc = {bias, bias, bias, bias};
#pragma unroll
            for (int kc = 0; kc < 4; kc++) {
                U4S8 t;
                t.u = *(const uint4*)(Wn3t16u + (size_t)c * 64 + kc * 16 + g * 4);
                acc = __builtin_amdgcn_mfma_f32_16x16x32_bf16(afr[kc], t.s, acc, 0, 0, 0);
            }
#pragma unroll
            for (int r = 0; r < 4; r++) hs3[g * 4 + r][c] = acc[r];
        }
    }
    __syncthreads();
    // phase 2 (MFMA, first 4 waves): [A|B](16x512) = h3 @ Wt16 -> LDS stA/stB
    if (tid < 256) {
        int wv = w, cl = lane & 15, g = lane >> 4;
        short8 afr[4];
#pragma unroll
        for (int kc = 0; kc < 4; kc++) {
            float4 lo = *(const float4*)(&hs3[cl][kc * 32 + g * 8]);
            float4 hi = *(const float4*)(&hs3[cl][kc * 32 + g * 8 + 4]);
            U4S8 t;
            t.u.x = packbf(lo.x, lo.y);
            t.u.y = packbf(lo.z, lo.w);
            t.u.z = packbf(hi.x, hi.y);
            t.u.w = packbf(hi.z, hi.w);
            afr[kc] = t.s;
        }
#pragma unroll
        for (int tt = 0; tt < 8; tt++) {
            int tile = wv * 8 + tt;
            int c = tile * 16 + cl;
            float bias = (tile < 16) ? bd1[c] : 0.0f;
            f32x4 acc = {bias, bias, bias, bias};
#pragma unroll
            for (int kc = 0; kc < 4; kc++) {
                U4S8 t;
                t.u = *(const uint4*)(Wt16u + (size_t)c * 64 + kc * 16 + g * 4);
                acc = __builtin_amdgcn_mfma_f32_16x16x32_bf16(afr[kc], t.s, acc, 0, 0, 0);
            }
            ushort* SP = (ushort*)((tile < 16) ? stA : stB);
            int oc = (tile < 16) ? c : (c - 256);
#pragma unroll
            for (int r = 0; r < 4; r++)
                SP[(g * 4 + r) * 264 + oc] = f2bf(acc[r]);
        }
    }
    // tail: o = 256 column, 4 lanes per node + shfl reduce -> LDS
    if (tid < 64) {
        int n = tid >> 2, j = tid & 3;
        float sA = 0.f, sB = 0.f;
        for (int k = j * 32; k < j * 32 + 32; k++) {
            float hv = hs3[n][k];
            sA = fmaf(hv, Wd1[k * 257 + 256], sA);
            sB = fmaf(hv, Wd1[(128 + k) * 257 + 256], sB);
        }
        sA += __shfl_xor(sA, 1, 64);
        sA += __shfl_xor(sA, 2, 64);
        sB += __shfl_xor(sB, 1, 64);
        sB += __shfl_xor(sB, 2, 64);
        if (j == 0) {
            ((ushort*)stA)[n * 264 + 256] = f2bf(sA + bd1[256]);
            ((ushort*)stB)[n * 264 + 256] = f2bf(sB);
        }
    }
    __syncthreads();
    // coalesced copy-out (all 16 waves): LDS row stride == global AB_U stride
    {
        int rows = N - nb; if (rows > 16) rows = 16;
        int tot2 = rows * 66;
        uint2* gA = (uint2*)(A16u + (size_t)nb * AB_U);
        uint2* gB = (uint2*)(B16u + (size_t)nb * AB_U);
        const uint2* sA = (const uint2*)stA;
        const uint2* sB = (const uint2*)stB;
        for (int idx = tid; idx < tot2; idx += 1024) {
            gA[idx] = sA[idx];
            gB[idx] = sB[idx];
        }
    }
}

// ---- decode edges, dst-grouped: wave/node, bf16 A gather, unroll 4, 7-shfl reduce ----
__global__ __launch_bounds__(256) void decodeE_kernel(
    const uint* __restrict__ A16u, const uint* __restrict__ B16u,
    const uint4* __restrict__ epack, const int* __restrict__ rowstart,
    const float* __restrict__ Wd1, const float* __restrict__ Wd2,
    const float* __restrict__ bd2, float* __restrict__ out, int N)
{
    int v = blockIdx.x * 4 + (threadIdx.x >> 6);
    int lane = threadIdx.x & 63;
    if (v >= N) return;
    const float* w256 = Wd1 + 256 * 257;
    float4 w2v = *(const float4*)(w256 + lane * 4);
    float4 wdv = *(const float4*)(Wd2 + lane * 4);
    const uint* Br = B16u + (size_t)v * AB_U;
    uint2 bp = *(const uint2*)(Br + lane * 2);
    float Bv0 = bf2f_lo(bp.x), Bv1 = bf2f_hi(bp.x);
    float Bv2 = bf2f_lo(bp.y), Bv3 = bf2f_hi(bp.y);
    float w2_l = w256[256], wd_l = Wd2[256], bd = bd2[0];
    float B_l = bf2f_lo(Br[128]);
    int beg = rowstart[v], end = rowstart[v + 1];
    int i = beg;
    for (; i + 4 <= end; i += 4) {
        uint4 pk[4];
        uint2 ap[4];
#pragma unroll
        for (int j = 0; j < 4; j++) pk[j] = epack[i + j];
#pragma unroll
        for (int j = 0; j < 4; j++)
            ap[j] = *(const uint2*)(A16u + (size_t)pk[j].y * AB_U + lane * 2);
        float acc[4];
#pragma unroll
        for (int j = 0; j < 4; j++) {
            float q = __uint_as_float(pk[j].w);
            float y0 = bf2f_lo(ap[j].x) + fmaf(q, w2v.x, Bv0);
            float y1 = bf2f_hi(ap[j].x) + fmaf(q, w2v.y, Bv1);
            float y2 = bf2f_lo(ap[j].y) + fmaf(q, w2v.z, Bv2);
            float y3 = bf2f_hi(ap[j].y) + fmaf(q, w2v.w, Bv3);
            acc[j] = fmaxf(y0, 0.f) * wdv.x + fmaxf(y1, 0.f) * wdv.y
                   + fmaxf(y2, 0.f) * wdv.z + fmaxf(y3, 0.f) * wdv.w;
        }
        int l1 = lane & 1, l2 = lane & 2;
        float s01 = l1 ? acc[0] : acc[1];
        float r01 = __shfl_xor(s01, 1, 64);
        float a01 = (l1 ? acc[1] : acc[0]) + r01;
        float s23 = l1 ? acc[2] : acc[3];
        float r23 = __shfl_xor(s23, 1, 64);
        float a23 = (l1 ? acc[3] : acc[2]) + r23;
        float sb = l2 ? a01 : a23;
        float rb = __shfl_xor(sb, 2, 64);
        float b = (l2 ? a23 : a01) + rb;
        b += __shfl_xor(b, 4, 64);
        b += __shfl_xor(b, 8, 64);
        b += __shfl_xor(b, 16, 64);
        b += __shfl_xor(b, 32, 64);
        uint ssel = l2 ? (l1 ? pk[3].y : pk[2].y) : (l1 ? pk[1].y : pk[0].y);
        uint esel = l2 ? (l1 ? pk[3].x : pk[2].x) : (l1 ? pk[1].x : pk[0].x);
        uint qsel = l2 ? (l1 ? pk[3].w : pk[2].w) : (l1 ? pk[1].w : pk[0].w);
        if (lane < 4) {
            float tl = bf2f_lo(A16u[(size_t)ssel * AB_U + 128]);
            float q = __uint_as_float(qsel);
            float tail = fmaxf(tl + fmaf(q, w2_l, B_l), 0.f) * wd_l;
            out[(int)esel] = b + tail + bd;
        }
    }
    for (; i < end; i++) {
        uint4 pk = epack[i];
        float q = __uint_as_float(pk.w);
        const uint* Ar = A16u + (size_t)pk.y * AB_U;
        uint2 ap = *(const uint2*)(Ar + lane * 2);
        float y0 = bf2f_lo(ap.x) + fmaf(q, w2v.x, Bv0);
        float y1 = bf2f_hi(ap.x) + fmaf(q, w2v.y, Bv1);
        float y2 = bf2f_lo(ap.y) + fmaf(q, w2v.z, Bv2);
        float y3 = bf2f_hi(ap.y) + fmaf(q, w2v.w, Bv3);
        float acc = fmaxf(y0, 0.f) * wdv.x + fmaxf(y1, 0.f) * wdv.y
                  + fmaxf(y2, 0.f) * wdv.z + fmaxf(y3, 0.f) * wdv.w;
        if (lane == 0) {
            float yl = bf2f_lo(Ar[128]) + fmaf(q, w2_l, B_l);
            acc = fmaf(fmaxf(yl, 0.f), wd_l, acc);
        }
#pragma unroll
        for (int off = 32; off > 0; off >>= 1) acc += __shfl_xor(acc, off, 64);
        if (lane == 0) out[(int)pk.x] = acc + bd;
    }
}

extern "C" void kernel_launch(void* const* d_in, const int* in_sizes, int n_in,
                              void* d_out, int out_size, void* d_ws, size_t ws_size,
                              hipStream_t stream) {
    (void)n_in; (void)out_size; (void)ws_size;
    const float* x   = (const float*)d_in[0];
    const float* ea  = (const float*)d_in[1];
    const float* qy  = (const float*)d_in[2];
    const int*   adj = (const int*)d_in[3];
    const float* t   = (const float*)d_in[4];
    // d_in[5]=num_steps (unused), d_in[6]=batch (unused)
    const float* We  = (const float*)d_in[7];
    const float* be  = (const float*)d_in[8];
    const float* Wo  = (const float*)d_in[9];
    const float* bo  = (const float*)d_in[10];
    const float* Wl1 = (const float*)d_in[11];
    const float* bl1 = (const float*)d_in[12];
    const float* Wn1 = (const float*)d_in[13];
    const float* bn1 = (const float*)d_in[14];
    const float* Wl2 = (const float*)d_in[15];
    const float* bl2 = (const float*)d_in[16];
    const float* Wn2 = (const float*)d_in[17];
    const float* bn2 = (const float*)d_in[18];
    const float* Wl3 = (const float*)d_in[19];
    const float* bl3 = (const float*)d_in[20];
    const float* Wn3 = (const float*)d_in[21];
    const float* bn3 = (const float*)d_in[22];
    const float* Wt1 = (const float*)d_in[23];
    const float* bt1 = (const float*)d_in[24];
    const float* Wt2 = (const float*)d_in[25];
    const float* bt2 = (const float*)d_in[26];
    const float* Wd1 = (const float*)d_in[27];
    const float* bd1 = (const float*)d_in[28];
    const float* Wd2 = (const float*)d_in[29];
    const float* bd2 = (const float*)d_in[30];
    float* out = (float*)d_out;

    int N = in_sizes[0];
    int E = in_sizes[3] / 2;
    const int* src = adj;
    const int* dst = adj + E;

    float* w    = (float*)d_ws;
    float* temb = w;            // wsmall block (1024 floats)
    float* P2   = w + 128;
    float* Q2   = w + 256;
    float* R2   = w + 384;
    float* P3   = w + 512;
    float* Q3   = w + 640;
    float* R3   = w + 768;
    float* scal = w + 896;
    float* agg1 = w + 1024;                          // N f32 (layer-1 scalar agg)
    uint*  hA     = (uint*)(agg1 + N);               // N*64 uints (bf16 pairs, layer-1 h)
    uint*  hB     = hA + (size_t)N * 64;             // N*64 uints (layer-2 h)
    uint*  A16u   = hB + (size_t)N * 64;             // N*AB_U uints
    uint*  B16u   = A16u + (size_t)N * AB_U;         // N*AB_U uints
    int* rowstart = (int*)(B16u + (size_t)N * AB_U); // N+1
    int* cursor   = rowstart + (N + 1);              // N
    int* partials = cursor + N;
    int nblk = (N + 1023) / 1024;
    char* pcur = (char*)(partials + nblk + 1);
    pcur = (char*)(((uintptr_t)pcur + 15) & ~(uintptr_t)15);
    uint4* epack = (uint4*)pcur;                     // E * 16B
    uint* Wt16u   = (uint*)(epack + E);              // 512*64 uints (bf16 Wd1^T)
    uint* Wn2t16u = Wt16u + 512 * 64;                // 128*64 uints
    uint* Wn3t16u = Wn2t16u + 128 * 64;              // 128*64 uints

    // ---- CSR build (by dst) ----
    hipMemsetAsync(cursor, 0, (size_t)N * sizeof(int), stream);
    hist_kernel<<<(E + 255) / 256, 256, 0, stream>>>(dst, cursor, E);
    scan1_kernel<<<nblk, 256, 0, stream>>>(cursor, rowstart, partials, N);
    scan2_kernel<<<1, 64, 0, stream>>>(partials, rowstart, nblk, N);
    scan3_kernel<<<(N + 255) / 256, 256, 0, stream>>>(rowstart, partials, N);
    hipMemsetAsync(cursor, 0, (size_t)N * sizeof(int), stream);
    scatter_kernel<<<(E + 255) / 256, 256, 0, stream>>>(src, dst, ea, qy, rowstart, cursor, epack, E);

    stage_kernel<<<768, 64, 0, stream>>>(Wd1, Wn2, Wn3, Wt16u, Wn2t16u, Wn3t16u);
    precompute_kernel<<<1, 256, 0, stream>>>(t, We, be, Wo, bo, Wl1, bl1,
                                             Wl2, bl2, Wl3, bl3,
                                             Wt1, bt1, Wt2, bt2, w);
    // layer 1
    edge1_kernel<<<(N + 255) / 256, 256, 0, stream>>>(x, epack, rowstart, scal, agg1, N);
    node1_kernel<<<(N * 64 + 255) / 256, 256, 0, stream>>>(x, agg1, Wn1, bn1, temb, hA, N);
    // layer 2 (fused agg + MFMA node update): hA -> hB
    aggnode2_kernel<<<(N + 15) / 16, 1024, 0, stream>>>(hA, epack, rowstart, P2, Q2, R2,
                                                        Wn2t16u, bn2, temb, hB, N);
    // layer 3 (fused agg + node MFMA + decode A/B): hB -> A16u/B16u
    aggnode3_kernel<<<(N + 15) / 16, 1024, 0, stream>>>(hB, epack, rowstart, P3, Q3, R3,
                                                        Wn3t16u, bn3, temb, Wt16u, Wd1, bd1,
                                                        A16u, B16u, N);
    // decode edges
    decodeE_kernel<<<(N + 3) / 4, 256, 0, stream>>>(A16u, B16u, epack, rowstart, Wd1, Wd2, bd2, out, N);
}

// Round 15
// 503.198 us; speedup vs baseline: 1.1122x; 1.1122x over previous
//
#include <hip/hip_runtime.h>

typedef unsigned int uint;
typedef unsigned short ushort;

#define AB_U 132  // A/B row stride in uints (264 bf16 elems, 257 used)

typedef __attribute__((ext_vector_type(8))) short short8;
typedef __attribute__((ext_vector_type(4))) float f32x4;
union U4S8 { uint4 u; short8 s; };

__device__ __forceinline__ ushort f2bf(float f) {
    uint u = __float_as_uint(f);
    u += 0x7FFFu + ((u >> 16) & 1u);   // round-to-nearest-even
    return (ushort)(u >> 16);
}
__device__ __forceinline__ float bf2f_lo(uint p) { return __uint_as_float(p << 16); }
__device__ __forceinline__ float bf2f_hi(uint p) { return __uint_as_float(p & 0xFFFF0000u); }
__device__ __forceinline__ uint packbf(float lo, float hi) {
    return (uint)f2bf(lo) | ((uint)f2bf(hi) << 16);
}

// ---------------- precompute: temb MLP + rank-2 edge-lin factors ----------------
__global__ __launch_bounds__(256) void precompute_kernel(
    const float* __restrict__ t,
    const float* __restrict__ We, const float* __restrict__ be,
    const float* __restrict__ Wo, const float* __restrict__ bo,
    const float* __restrict__ Wl1, const float* __restrict__ bl1,
    const float* __restrict__ Wl2, const float* __restrict__ bl2,
    const float* __restrict__ Wl3, const float* __restrict__ bl3,
    const float* __restrict__ Wt1, const float* __restrict__ bt1,
    const float* __restrict__ Wt2, const float* __restrict__ bt2,
    float* __restrict__ wsmall)
{
    __shared__ float t0[128];
    __shared__ float y1[256];
    int tid = threadIdx.x;
    float tt = t[0] * 4.0f;
    if (tid < 64) {
        float f = expf(-logf(10000.0f) * (float)tid / 63.0f);
        float v = tt * f;
        t0[tid]      = sinf(v);
        t0[tid + 64] = cosf(v);
    }
    __syncthreads();
    {
        float acc = bt1[tid];
        for (int k = 0; k < 128; k++) acc = fmaf(t0[k], Wt1[k * 256 + tid], acc);
        y1[tid] = fmaxf(acc, 0.0f);
    }
    __syncthreads();
    if (tid < 128) {
        float a = bt2[tid];
        for (int k = 0; k < 256; k++) a = fmaf(y1[k], Wt2[k * 128 + tid], a);
        wsmall[tid] = a;  // temb
    }
    {
        int j = tid & 127;
        const float* Wl  = (tid < 128) ? Wl2 : Wl3;
        const float* blp = (tid < 128) ? bl2 : bl3;
        float p = 0.f, q = 0.f, r = blp[j];
        for (int k = 0; k < 64; k++) {
            float w1 = Wl[k * 128 + j], w2 = Wl[(64 + k) * 128 + j];
            p = fmaf(We[k], w1, p);
            q = fmaf(Wo[k], w2, q);
            r = fmaf(be[k], w1, r);
            r = fmaf(bo[k], w2, r);
        }
        int base = (tid < 128) ? 128 : 512;
        wsmall[base + j]       = p;
        wsmall[base + 128 + j] = q;
        wsmall[base + 256 + j] = r;
    }
    if (tid == 0) {
        float p1 = 0.f, q1 = 0.f, r1 = bl1[0];
        for (int k = 0; k < 64; k++) {
            p1 = fmaf(We[k], Wl1[k], p1);
            q1 = fmaf(Wo[k], Wl1[64 + k], q1);
            r1 = fmaf(be[k], Wl1[k], r1);
            r1 = fmaf(bo[k], Wl1[64 + k], r1);
        }
        wsmall[896] = p1; wsmall[897] = q1; wsmall[898] = r1;
    }
}

// merged weight staging: c<512 -> Wd1 (A|B cols), 512..639 -> Wn2, 640..767 -> Wn3
__global__ __launch_bounds__(64) void stage_kernel(
    const float* __restrict__ Wd1, const float* __restrict__ Wn2,
    const float* __restrict__ Wn3, uint* __restrict__ Wt16u,
    uint* __restrict__ Wn2t16u, uint* __restrict__ Wn3t16u)
{
    int c = blockIdx.x, u = threadIdx.x, k = u * 2;
    if (c < 256) {
        Wt16u[c * 64 + u] = packbf(Wd1[k * 257 + c], Wd1[(k + 1) * 257 + c]);
    } else if (c < 512) {
        int cc = c - 256;
        Wt16u[c * 64 + u] = packbf(Wd1[(128 + k) * 257 + cc], Wd1[(128 + k + 1) * 257 + cc]);
    } else if (c < 640) {
        int cc = c - 512;
        Wn2t16u[cc * 64 + u] = packbf(Wn2[k * 128 + cc], Wn2[(k + 1) * 128 + cc]);
    } else {
        int cc = c - 640;
        Wn3t16u[cc * 64 + u] = packbf(Wn3[k * 128 + cc], Wn3[(k + 1) * 128 + cc]);
    }
}

// ---------------- CSR build: histogram -> hierarchical scan -> scatter ----------------
__global__ __launch_bounds__(256) void hist_kernel(
    const int* __restrict__ dst, int* __restrict__ cnt, int E)
{
    int e = blockIdx.x * blockDim.x + threadIdx.x;
    if (e < E) atomicAdd(&cnt[dst[e]], 1);
}

__global__ __launch_bounds__(256) void scan1_kernel(
    const int* __restrict__ cnt, int* __restrict__ rowstart,
    int* __restrict__ partials, int N)
{
    __shared__ int wsum[4];
    int b = blockIdx.x;
    int tid = threadIdx.x, lane = tid & 63, w = tid >> 6;
    int i0 = b * 1024 + tid * 4;
    int v0 = (i0     < N) ? cnt[i0]     : 0;
    int v1 = (i0 + 1 < N) ? cnt[i0 + 1] : 0;
    int v2 = (i0 + 2 < N) ? cnt[i0 + 2] : 0;
    int v3 = (i0 + 3 < N) ? cnt[i0 + 3] : 0;
    int tsum = v0 + v1 + v2 + v3;
    int s = tsum;
#pragma unroll
    for (int off = 1; off < 64; off <<= 1) {
        int u = __shfl_up(s, off, 64);
        if (lane >= off) s += u;
    }
    if (lane == 63) wsum[w] = s;
    __syncthreads();
    int woff = 0;
    for (int k = 0; k < w; k++) woff += wsum[k];
    int ex = woff + s - tsum;
    if (i0     < N) rowstart[i0]     = ex;
    if (i0 + 1 < N) rowstart[i0 + 1] = ex + v0;
    if (i0 + 2 < N) rowstart[i0 + 2] = ex + v0 + v1;
    if (i0 + 3 < N) rowstart[i0 + 3] = ex + v0 + v1 + v2;
    if (tid == 255) partials[b] = woff + s;
}

__global__ __launch_bounds__(64) void scan2_kernel(
    int* __restrict__ partials, int* __restrict__ rowstart, int nblk, int N)
{
    int lane = threadIdx.x;
    int carry = 0;
    for (int base = 0; base < nblk; base += 64) {
        int i = base + lane;
        int v = (i < nblk) ? partials[i] : 0;
        int s = v;
#pragma unroll
        for (int off = 1; off < 64; off <<= 1) {
            int u = __shfl_up(s, off, 64);
            if (lane >= off) s += u;
        }
        if (i < nblk) partials[i] = carry + s - v;
        carry += __shfl(s, 63, 64);
    }
    if (lane == 0) rowstart[N] = carry;
}

__global__ __launch_bounds__(256) void scan3_kernel(
    int* __restrict__ rowstart, const int* __restrict__ partials, int N)
{
    int i = blockIdx.x * blockDim.x + threadIdx.x;
    if (i < N) rowstart[i] += partials[i >> 10];
}

__global__ __launch_bounds__(256) void scatter_kernel(
    const int* __restrict__ src, const int* __restrict__ dst,
    const float* __restrict__ ea, const float* __restrict__ qy,
    const int* __restrict__ rowstart, int* __restrict__ cursor,
    uint4* __restrict__ epack, int E)
{
    int e = blockIdx.x * blockDim.x + threadIdx.x;
    if (e >= E) return;
    int d = dst[e];
    int pos = atomicAdd(&cursor[d], 1);
    uint4 pk;
    pk.x = (uint)e;
    pk.y = (uint)src[e];
    pk.z = __float_as_uint(ea[e]);
    pk.w = __float_as_uint(qy[e]);
    epack[rowstart[d] + pos] = pk;
}

// ----- layer 1 (scalar channel), pull over CSR, unroll 2; writes v = x + agg1 -----
__global__ __launch_bounds__(256) void edge1_kernel(
    const float* __restrict__ x, const uint4* __restrict__ epack,
    const int* __restrict__ rowstart, const float* __restrict__ scal,
    float* __restrict__ vout, int N)
{
    int v = blockIdx.x * blockDim.x + threadIdx.x;
    if (v >= N) return;
    float s0 = scal[0], s1 = scal[1], s2 = scal[2];
    int beg = rowstart[v], end = rowstart[v + 1];
    float m = 0.0f;
    int i = beg;
    for (; i + 2 <= end; i += 2) {
        uint4 pk0 = epack[i];
        uint4 pk1 = epack[i + 1];
        float x0 = x[(int)pk0.y];
        float x1 = x[(int)pk1.y];
        m += fmaxf(x0 + fmaf(__uint_as_float(pk0.z), s0, fmaf(__uint_as_float(pk0.w), s1, s2)), 0.0f);
        m += fmaxf(x1 + fmaf(__uint_as_float(pk1.z), s0, fmaf(__uint_as_float(pk1.w), s1, s2)), 0.0f);
    }
    if (i < end) {
        uint4 pk = epack[i];
        m += fmaxf(x[(int)pk.y] + fmaf(__uint_as_float(pk.z), s0, fmaf(__uint_as_float(pk.w), s1, s2)), 0.0f);
    }
    vout[v] = x[v] + m;
}

// --- layer-2 aggregation via rank-1 h1: gather scalar v[src], reconstruct message ---
__global__ __launch_bounds__(256) void aggL2v_kernel(
    const float* __restrict__ v, const uint4* __restrict__ epack,
    const int* __restrict__ rowstart,
    const float* __restrict__ P, const float* __restrict__ Q,
    const float* __restrict__ R, const float* __restrict__ Wn1,
    const float* __restrict__ bn1, const float* __restrict__ temb,
    uint* __restrict__ agg16u, int N)
{
    int vn = blockIdx.x * 4 + (threadIdx.x >> 6);
    int lane = threadIdx.x & 63;
    if (vn >= N) return;
    int c = lane * 2;
    float2 Pv = *(const float2*)(P + c);
    float2 Qv = *(const float2*)(Q + c);
    float2 Rv = *(const float2*)(R + c);
    float2 w1 = *(const float2*)(Wn1 + c);
    Rv.x += bn1[c] + temb[c];           // fold h1 bias into R
    Rv.y += bn1[c + 1] + temb[c + 1];
    int beg = rowstart[vn], end = rowstart[vn + 1];
    float accx = 0.0f, accy = 0.0f;
    int i = beg;
    for (; i + 8 <= end; i += 8) {
        uint4 pk[8];
        float vv[8];
#pragma unroll
        for (int j = 0; j < 8; j++) pk[j] = epack[i + j];
#pragma unroll
        for (int j = 0; j < 8; j++) vv[j] = v[(int)pk[j].y];
#pragma unroll
        for (int j = 0; j < 8; j++) {
            float a = __uint_as_float(pk[j].z), b = __uint_as_float(pk[j].w);
            accx += fmaxf(fmaf(vv[j], w1.x, fmaf(a, Pv.x, fmaf(b, Qv.x, Rv.x))), 0.0f);
            accy += fmaxf(fmaf(vv[j], w1.y, fmaf(a, Pv.y, fmaf(b, Qv.y, Rv.y))), 0.0f);
        }
    }
    for (; i < end; i++) {
        uint4 pk = epack[i];
        float a = __uint_as_float(pk.z), b = __uint_as_float(pk.w);
        float vv = v[(int)pk.y];
        accx += fmaxf(fmaf(vv, w1.x, fmaf(a, Pv.x, fmaf(b, Qv.x, Rv.x))), 0.0f);
        accy += fmaxf(fmaf(vv, w1.y, fmaf(a, Pv.y, fmaf(b, Qv.y, Rv.y))), 0.0f);
    }
    agg16u[(size_t)vn * 64 + lane] = packbf(accx, accy);
}

// ------------ layer 3 aggregation: pull over hB rows (bf16), unroll 8 ------------
__global__ __launch_bounds__(256) void aggL_kernel(
    const uint* __restrict__ h16u, const uint4* __restrict__ epack,
    const int* __restrict__ rowstart,
    const float* __restrict__ P, const float* __restrict__ Q,
    const float* __restrict__ R, uint* __restrict__ agg16u, int N)
{
    int v = blockIdx.x * 4 + (threadIdx.x >> 6);
    int lane = threadIdx.x & 63;
    if (v >= N) return;
    int c = lane * 2;
    float2 Pv = *(const float2*)(P + c);
    float2 Qv = *(const float2*)(Q + c);
    float2 Rv = *(const float2*)(R + c);
    int beg = rowstart[v], end = rowstart[v + 1];
    float accx = 0.0f, accy = 0.0f;
    int i = beg;
    for (; i + 8 <= end; i += 8) {
        uint4 pk[8];
        uint hp[8];
#pragma unroll
        for (int j = 0; j < 8; j++) pk[j] = epack[i + j];
#pragma unroll
        for (int j = 0; j < 8; j++) hp[j] = h16u[(size_t)pk[j].y * 64 + lane];
#pragma unroll
        for (int j = 0; j < 8; j++) {
            float a = __uint_as_float(pk[j].z), b = __uint_as_float(pk[j].w);
            accx += fmaxf(bf2f_lo(hp[j]) + fmaf(a, Pv.x, fmaf(b, Qv.x, Rv.x)), 0.0f);
            accy += fmaxf(bf2f_hi(hp[j]) + fmaf(a, Pv.y, fmaf(b, Qv.y, Rv.y)), 0.0f);
        }
    }
    for (; i + 2 <= end; i += 2) {
        uint4 pk0 = epack[i];
        uint4 pk1 = epack[i + 1];
        uint hp0 = h16u[(size_t)pk0.y * 64 + lane];
        uint hp1 = h16u[(size_t)pk1.y * 64 + lane];
        float a0 = __uint_as_float(pk0.z), b0 = __uint_as_float(pk0.w);
        float a1 = __uint_as_float(pk1.z), b1 = __uint_as_float(pk1.w);
        accx += fmaxf(bf2f_lo(hp0) + fmaf(a0, Pv.x, fmaf(b0, Qv.x, Rv.x)), 0.0f);
        accy += fmaxf(bf2f_hi(hp0) + fmaf(a0, Pv.y, fmaf(b0, Qv.y, Rv.y)), 0.0f);
        accx += fmaxf(bf2f_lo(hp1) + fmaf(a1, Pv.x, fmaf(b1, Qv.x, Rv.x)), 0.0f);
        accy += fmaxf(bf2f_hi(hp1) + fmaf(a1, Pv.y, fmaf(b1, Qv.y, Rv.y)), 0.0f);
    }
    if (i < end) {
        uint4 pk = epack[i];
        float a = __uint_as_float(pk.z), b = __uint_as_float(pk.w);
        uint hp = h16u[(size_t)pk.y * 64 + lane];
        accx += fmaxf(bf2f_lo(hp) + fmaf(a, Pv.x, fmaf(b, Qv.x, Rv.x)), 0.0f);
        accy += fmaxf(bf2f_hi(hp) + fmaf(a, Pv.y, fmaf(b, Qv.y, Rv.y)), 0.0f);
    }
    agg16u[(size_t)v * 64 + lane] = packbf(accx, accy);
}

// ----- layer 2 node update via MFMA: h2 = (v*Wn1+bb1 + agg2) @ Wn2 + bn2 + temb -----
__global__ __launch_bounds__(256) void nodeL_kernel(
    const float* __restrict__ v, const float* __restrict__ Wn1,
    const float* __restrict__ bn1, const uint* __restrict__ agg16u,
    const uint* __restrict__ Wn2t16u, const float* __restrict__ bn,
    const float* __restrict__ temb, uint* __restrict__ hB, int N)
{
    __shared__ uint vs16[64][68];   // (h1+agg) bf16 pairs, 17.4 KB
    int nb = blockIdx.x * 64;
    int tid = threadIdx.x;
    for (int idx = tid; idx < 64 * 64; idx += 256) {
        int n = idx >> 6, l = idx & 63;
        uint pk = 0;
        if (nb + n < N) {
            float vv = v[nb + n];
            uint gp = agg16u[(size_t)(nb + n) * 64 + l];
            int c = l * 2;
            float h0 = fmaf(vv, Wn1[c],     bn1[c]     + temb[c])     + bf2f_lo(gp);
            float h1 = fmaf(vv, Wn1[c + 1], bn1[c + 1] + temb[c + 1]) + bf2f_hi(gp);
            pk = packbf(h0, h1);
        }
        vs16[n][l] = pk;
    }
    __syncthreads();
    int wv = tid >> 6, lane = tid & 63, cl = lane & 15, g = lane >> 4;
    int rbase = wv * 16;
    short8 afr[4];
#pragma unroll
    for (int kc = 0; kc < 4; kc++) {
        U4S8 t;
        t.u = *(const uint4*)(&vs16[rbase + cl][kc * 16 + g * 4]);
        afr[kc] = t.s;
    }
#pragma unroll
    for (int tt = 0; tt < 8; tt++) {
        int c = tt * 16 + cl;
        float bias = bn[c] + temb[c];
        f32x4 acc = {bias, bias, bias, bias};
#pragma unroll
        for (int kc = 0; kc < 4; kc++) {
            U4S8 t;
            t.u = *(const uint4*)(Wn2t16u + (size_t)c * 64 + kc * 16 + g * 4);
            acc = __builtin_amdgcn_mfma_f32_16x16x32_bf16(afr[kc], t.s, acc, 0, 0, 0);
        }
#pragma unroll
        for (int r = 0; r < 4; r++) {
            int n = nb + rbase + g * 4 + r;
            float val = acc[r];
            float nbr = __shfl_down(val, 1, 64);
            if (n < N && (cl & 1) == 0)
                hB[(size_t)n * 64 + (c >> 1)] = packbf(val, nbr);
        }
    }
}

// ------- fused layer-3 node update + decode A/B precompute, all-MFMA, LDS-staged out
__global__ __launch_bounds__(256) void node3_decode_kernel(
    const uint* __restrict__ h16u, const uint* __restrict__ agg16u,
    const uint* __restrict__ Wn3t16u, const float* __restrict__ bn3,
    const float* __restrict__ temb, const uint* __restrict__ Wt16u,
    const float* __restrict__ Wd1, const float* __restrict__ bd1,
    uint* __restrict__ A16u, uint* __restrict__ B16u, int N)
{
    __shared__ uint vs16[16][68];    // (h+agg) bf16 pairs, 4.35 KB
    __shared__ float hs3[16][132];   // h3 f32, 8.45 KB
    __shared__ uint stA[16 * 132];   // A block bf16, 8.45 KB
    __shared__ uint stB[16 * 132];   // B block bf16, 8.45 KB
    int nb = blockIdx.x * 16;
    int tid = threadIdx.x;
    for (int idx = tid; idx < 16 * 32; idx += 256) {   // uint2 per idx
        int n = idx >> 5, u2 = (idx & 31) * 2;
        uint2 pk = make_uint2(0, 0);
        if (nb + n < N) {
            uint2 hp = *(const uint2*)(h16u + (size_t)(nb + n) * 64 + u2);
            uint2 gp = *(const uint2*)(agg16u + (size_t)(nb + n) * 64 + u2);
            pk.x = packbf(bf2f_lo(hp.x) + bf2f_lo(gp.x), bf2f_hi(hp.x) + bf2f_hi(gp.x));
            pk.y = packbf(bf2f_lo(hp.y) + bf2f_lo(gp.y), bf2f_hi(hp.y) + bf2f_hi(gp.y));
        }
        *(uint2*)(&vs16[n][u2]) = pk;
    }
    __syncthreads();
    int wv = tid >> 6, lane = tid & 63, cl = lane & 15, g = lane >> 4;
    // phase 1 (MFMA): h3(16x128) = vs(16x128) @ Wn3(128x128) + bn3 + temb -> hs3 f32
    {
        short8 afr[4];
#pragma unroll
        for (int kc = 0; kc < 4; kc++) {
            U4S8 t;
            t.u = *(const uint4*)(&vs16[cl][kc * 16 + g * 4]);
            afr[kc] = t.s;
        }
#pragma unroll
        for (int tt = 0; tt < 2; tt++) {
            int c = wv * 32 + tt * 16 + cl;
            float bias = bn3[c] + temb[c];
            f32x4 acc = {bias, bias, bias, bias};
#pragma unroll
            for (int kc = 0; kc < 4; kc++) {
                U4S8 t;
                t.u = *(const uint4*)(Wn3t16u + (size_t)c * 64 + kc * 16 + g * 4);
                acc = __builtin_amdgcn_mfma_f32_16x16x32_bf16(afr[kc], t.s, acc, 0, 0, 0);
            }
#pragma unroll
            for (int r = 0; r < 4; r++) hs3[g * 4 + r][c] = acc[r];
        }
    }
    __syncthreads();
    // phase 2 (MFMA): [A|B](16x512) = h3 @ Wt16 ; results staged in LDS
    {
        short8 afr[4];
#pragma unroll
        for (int kc = 0; kc < 4; kc++) {
            float4 lo = *(const float4*)(&hs3[cl][kc * 32 + g * 8]);
            float4 hi = *(const float4*)(&hs3[cl][kc * 32 + g * 8 + 4]);
            U4S8 t;
            t.u.x = packbf(lo.x, lo.y);
            t.u.y = packbf(lo.z, lo.w);
            t.u.z = packbf(hi.x, hi.y);
            t.u.w = packbf(hi.z, hi.w);
            afr[kc] = t.s;
        }
#pragma unroll
        for (int tt = 0; tt < 8; tt++) {
            int tile = wv * 8 + tt;
            int c = tile * 16 + cl;
            float bias = (tile < 16) ? bd1[c] : 0.0f;
            f32x4 acc = {bias, bias, bias, bias};
#pragma unroll
            for (int kc = 0; kc < 4; kc++) {
                U4S8 t;
                t.u = *(const uint4*)(Wt16u + (size_t)c * 64 + kc * 16 + g * 4);
                acc = __builtin_amdgcn_mfma_f32_16x16x32_bf16(afr[kc], t.s, acc, 0, 0, 0);
            }
            ushort* SP = (ushort*)((tile < 16) ? stA : stB);
            int oc = (tile < 16) ? c : (c - 256);
#pragma unroll
            for (int r = 0; r < 4; r++)
                SP[(g * 4 + r) * 264 + oc] = f2bf(acc[r]);
        }
    }
    // tail: o = 256 column, 4 lanes per node + shfl reduce -> LDS
    if (tid < 64) {
        int n = tid >> 2, j = tid & 3;
        float sA = 0.f, sB = 0.f;
        for (int k = j * 32; k < j * 32 + 32; k++) {
            float hv = hs3[n][k];
            sA = fmaf(hv, Wd1[k * 257 + 256], sA);
            sB = fmaf(hv, Wd1[(128 + k) * 257 + 256], sB);
        }
        sA += __shfl_xor(sA, 1, 64);
        sA += __shfl_xor(sA, 2, 64);
        sB += __shfl_xor(sB, 1, 64);
        sB += __shfl_xor(sB, 2, 64);
        if (j == 0) {
            ((ushort*)stA)[n * 264 + 256] = f2bf(sA + bd1[256]);
            ((ushort*)stB)[n * 264 + 256] = f2bf(sB);
        }
    }
    __syncthreads();
    // coalesced copy-out: LDS row stride (132 uints) == global AB_U stride
    {
        int rows = N - nb; if (rows > 16) rows = 16;
        int tot2 = rows * 66;
        uint2* gA = (uint2*)(A16u + (size_t)nb * AB_U);
        uint2* gB = (uint2*)(B16u + (size_t)nb * AB_U);
        const uint2* sA = (const uint2*)stA;
        const uint2* sB = (const uint2*)stB;
        for (int idx = tid; idx < tot2; idx += 256) {
            gA[idx] = sA[idx];
            gB[idx] = sB[idx];
        }
    }
}

// ---- decode edges, dst-grouped: wave/node, bf16 A gather, unroll 4, 7-shfl reduce ----
__global__ __launch_bounds__(256) void decodeE_kernel(
    const uint* __restrict__ A16u, const uint* __restrict__ B16u,
    const uint4* __restrict__ epack, const int* __restrict__ rowstart,
    const float* __restrict__ Wd1, const float* __restrict__ Wd2,
    const float* __restrict__ bd2, float* __restrict__ out, int N)
{
    int v = blockIdx.x * 4 + (threadIdx.x >> 6);
    int lane = threadIdx.x & 63;
    if (v >= N) return;
    const float* w256 = Wd1 + 256 * 257;
    float4 w2v = *(const float4*)(w256 + lane * 4);
    float4 wdv = *(const float4*)(Wd2 + lane * 4);
    const uint* Br = B16u + (size_t)v * AB_U;
    uint2 bp = *(const uint2*)(Br + lane * 2);
    float Bv0 = bf2f_lo(bp.x), Bv1 = bf2f_hi(bp.x);
    float Bv2 = bf2f_lo(bp.y), Bv3 = bf2f_hi(bp.y);
    float w2_l = w256[256], wd_l = Wd2[256], bd = bd2[0];
    float B_l = bf2f_lo(Br[128]);
    int beg = rowstart[v], end = rowstart[v + 1];
    int i = beg;
    for (; i + 4 <= end; i += 4) {
        uint4 pk[4];
        uint2 ap[4];
#pragma unroll
        for (int j = 0; j < 4; j++) pk[j] = epack[i + j];
#pragma unroll
        for (int j = 0; j < 4; j++)
            ap[j] = *(const uint2*)(A16u + (size_t)pk[j].y * AB_U + lane * 2);
        float acc[4];
#pragma unroll
        for (int j = 0; j < 4; j++) {
            float q = __uint_as_float(pk[j].w);
            float y0 = bf2f_lo(ap[j].x) + fmaf(q, w2v.x, Bv0);
            float y1 = bf2f_hi(ap[j].x) + fmaf(q, w2v.y, Bv1);
            float y2 = bf2f_lo(ap[j].y) + fmaf(q, w2v.z, Bv2);
            float y3 = bf2f_hi(ap[j].y) + fmaf(q, w2v.w, Bv3);
            acc[j] = fmaxf(y0, 0.f) * wdv.x + fmaxf(y1, 0.f) * wdv.y
                   + fmaxf(y2, 0.f) * wdv.z + fmaxf(y3, 0.f) * wdv.w;
        }
        int l1 = lane & 1, l2 = lane & 2;
        float s01 = l1 ? acc[0] : acc[1];
        float r01 = __shfl_xor(s01, 1, 64);
        float a01 = (l1 ? acc[1] : acc[0]) + r01;
        float s23 = l1 ? acc[2] : acc[3];
        float r23 = __shfl_xor(s23, 1, 64);
        float a23 = (l1 ? acc[3] : acc[2]) + r23;
        float sb = l2 ? a01 : a23;
        float rb = __shfl_xor(sb, 2, 64);
        float b = (l2 ? a23 : a01) + rb;
        b += __shfl_xor(b, 4, 64);
        b += __shfl_xor(b, 8, 64);
        b += __shfl_xor(b, 16, 64);
        b += __shfl_xor(b, 32, 64);
        uint ssel = l2 ? (l1 ? pk[3].y : pk[2].y) : (l1 ? pk[1].y : pk[0].y);
        uint esel = l2 ? (l1 ? pk[3].x : pk[2].x) : (l1 ? pk[1].x : pk[0].x);
        uint qsel = l2 ? (l1 ? pk[3].w : pk[2].w) : (l1 ? pk[1].w : pk[0].w);
        if (lane < 4) {
            float tl = bf2f_lo(A16u[(size_t)ssel * AB_U + 128]);
            float q = __uint_as_float(qsel);
            float tail = fmaxf(tl + fmaf(q, w2_l, B_l), 0.f) * wd_l;
            out[(int)esel] = b + tail + bd;
        }
    }
    for (; i < end; i++) {
        uint4 pk = epack[i];
        float q = __uint_as_float(pk.w);
        const uint* Ar = A16u + (size_t)pk.y * AB_U;
        uint2 ap = *(const uint2*)(Ar + lane * 2);
        float y0 = bf2f_lo(ap.x) + fmaf(q, w2v.x, Bv0);
        float y1 = bf2f_hi(ap.x) + fmaf(q, w2v.y, Bv1);
        float y2 = bf2f_lo(ap.y) + fmaf(q, w2v.z, Bv2);
        float y3 = bf2f_hi(ap.y) + fmaf(q, w2v.w, Bv3);
        float acc = fmaxf(y0, 0.f) * wdv.x + fmaxf(y1, 0.f) * wdv.y
                  + fmaxf(y2, 0.f) * wdv.z + fmaxf(y3, 0.f) * wdv.w;
        if (lane == 0) {
            float yl = bf2f_lo(Ar[128]) + fmaf(q, w2_l, B_l);
            acc = fmaf(fmaxf(yl, 0.f), wd_l, acc);
        }
#pragma unroll
        for (int off = 32; off > 0; off >>= 1) acc += __shfl_xor(acc, off, 64);
        if (lane == 0) out[(int)pk.x] = acc + bd;
    }
}

extern "C" void kernel_launch(void* const* d_in, const int* in_sizes, int n_in,
                              void* d_out, int out_size, void* d_ws, size_t ws_size,
                              hipStream_t stream) {
    (void)n_in; (void)out_size; (void)ws_size;
    const float* x   = (const float*)d_in[0];
    const float* ea  = (const float*)d_in[1];
    const float* qy  = (const float*)d_in[2];
    const int*   adj = (const int*)d_in[3];
    const float* t   = (const float*)d_in[4];
    // d_in[5]=num_steps (unused), d_in[6]=batch (unused)
    const float* We  = (const float*)d_in[7];
    const float* be  = (const float*)d_in[8];
    const float* Wo  = (const float*)d_in[9];
    const float* bo  = (const float*)d_in[10];
    const float* Wl1 = (const float*)d_in[11];
    const float* bl1 = (const float*)d_in[12];
    const float* Wn1 = (const float*)d_in[13];
    const float* bn1 = (const float*)d_in[14];
    const float* Wl2 = (const float*)d_in[15];
    const float* bl2 = (const float*)d_in[16];
    const float* Wn2 = (const float*)d_in[17];
    const float* bn2 = (const float*)d_in[18];
    const float* Wl3 = (const float*)d_in[19];
    const float* bl3 = (const float*)d_in[20];
    const float* Wn3 = (const float*)d_in[21];
    const float* bn3 = (const float*)d_in[22];
    const float* Wt1 = (const float*)d_in[23];
    const float* bt1 = (const float*)d_in[24];
    const float* Wt2 = (const float*)d_in[25];
    const float* bt2 = (const float*)d_in[26];
    const float* Wd1 = (const float*)d_in[27];
    const float* bd1 = (const float*)d_in[28];
    const float* Wd2 = (const float*)d_in[29];
    const float* bd2 = (const float*)d_in[30];
    float* out = (float*)d_out;

    int N = in_sizes[0];
    int E = in_sizes[3] / 2;
    const int* src = adj;
    const int* dst = adj + E;

    float* w    = (float*)d_ws;
    float* temb = w;            // wsmall block (1024 floats)
    float* P2   = w + 128;
    float* Q2   = w + 256;
    float* R2   = w + 384;
    float* P3   = w + 512;
    float* Q3   = w + 640;
    float* R3   = w + 768;
    float* scal = w + 896;
    float* v    = w + 1024;                          // N f32 (x + agg1)
    uint*  hB     = (uint*)(v + N);                  // N*64 uints (layer-2 h, bf16 pairs)
    uint*  agg16u = hB + (size_t)N * 64;             // N*64 uints (bf16 pairs)
    uint*  A16u   = agg16u + (size_t)N * 64;         // N*AB_U uints
    uint*  B16u   = A16u + (size_t)N * AB_U;         // N*AB_U uints
    int* rowstart = (int*)(B16u + (size_t)N * AB_U); // N+1
    int* cursor   = rowstart + (N + 1);              // N
    int* partials = cursor + N;
    int nblk = (N + 1023) / 1024;
    char* pcur = (char*)(partials + nblk + 1);
    pcur = (char*)(((uintptr_t)pcur + 15) & ~(uintptr_t)15);
    uint4* epack = (uint4*)pcur;                     // E * 16B
    uint* Wt16u   = (uint*)(epack + E);              // 512*64 uints (bf16 Wd1^T)
    uint* Wn2t16u = Wt16u + 512 * 64;                // 128*64 uints
    uint* Wn3t16u = Wn2t16u + 128 * 64;              // 128*64 uints

    // ---- CSR build (by dst) ----
    hipMemsetAsync(cursor, 0, (size_t)N * sizeof(int), stream);
    hist_kernel<<<(E + 255) / 256, 256, 0, stream>>>(dst, cursor, E);
    scan1_kernel<<<nblk, 256, 0, stream>>>(cursor, rowstart, partials, N);
    scan2_kernel<<<1, 64, 0, stream>>>(partials, rowstart, nblk, N);
    scan3_kernel<<<(N + 255) / 256, 256, 0, stream>>>(rowstart, partials, N);
    hipMemsetAsync(cursor, 0, (size_t)N * sizeof(int), stream);
    scatter_kernel<<<(E + 255) / 256, 256, 0, stream>>>(src, dst, ea, qy, rowstart, cursor, epack, E);

    stage_kernel<<<768, 64, 0, stream>>>(Wd1, Wn2, Wn3, Wt16u, Wn2t16u, Wn3t16u);
    precompute_kernel<<<1, 256, 0, stream>>>(t, We, be, Wo, bo, Wl1, bl1,
                                             Wl2, bl2, Wl3, bl3,
                                             Wt1, bt1, Wt2, bt2, w);
    // layer 1: v = x + agg1  (h1 stays rank-1, never materialized)
    edge1_kernel<<<(N + 255) / 256, 256, 0, stream>>>(x, epack, rowstart, scal, v, N);
    // layer 2: scalar-gather aggregation + MFMA node update -> hB
    aggL2v_kernel<<<(N + 3) / 4, 256, 0, stream>>>(v, epack, rowstart, P2, Q2, R2,
                                                   Wn1, bn1, temb, agg16u, N);
    nodeL_kernel<<<(N + 63) / 64, 256, 0, stream>>>(v, Wn1, bn1, agg16u, Wn2t16u,
                                                    bn2, temb, hB, N);
    // layer 3: row-gather aggregation + fused node MFMA + decode A/B
    aggL_kernel<<<(N + 3) / 4, 256, 0, stream>>>(hB, epack, rowstart, P3, Q3, R3, agg16u, N);
    node3_decode_kernel<<<(N + 15) / 16, 256, 0, stream>>>(hB, agg16u, Wn3t16u, bn3, temb,
                                                           Wt16u, Wd1, bd1,
                                                           A16u, B16u, N);
    // decode edges
    decodeE_kernel<<<(N + 3) / 4, 256, 0, stream>>>(A16u, B16u, epack, rowstart, Wd1, Wd2, bd2, out, N);
}